// Round 3
// baseline (775.301 us; speedup 1.0000x reference)
//
#include <hip/hip_runtime.h>

// Shapes: S=1024 qlen, B=4 bsz, E=768 d_embed, D=1024 d_model, H=16 heads, Dh=64.
// M = S*B = 4096 rows everywhere (row m = i*4 + b).
#define LOG2E 1.44269504088896340736f

typedef __attribute__((ext_vector_type(8))) short short8;   // 8 x bf16 fragment
typedef __attribute__((ext_vector_type(4))) short short4v;  // 4 x bf16 (8B)
typedef __attribute__((ext_vector_type(4))) float floatx4;  // MFMA C/D fragment

__device__ __forceinline__ float bf2f(short s) {
    union { float f; unsigned u; } v; v.u = ((unsigned)(unsigned short)s) << 16; return v.f;
}
__device__ __forceinline__ short f2bf(float f) {
    union { float f; unsigned u; } v; v.f = f;
    unsigned u = v.u;
    u += 0x7FFFu + ((u >> 16) & 1u);   // RNE
    return (short)(u >> 16);
}

// async global->LDS, 16B per lane; LDS dest = wave-uniform base + lane*16
__device__ __forceinline__ void gl_lds16(const void* g, void* l) {
    __builtin_amdgcn_global_load_lds((const __attribute__((address_space(1))) void*)g,
                                     (__attribute__((address_space(3))) void*)l, 16, 0, 0);
}

// ---------------- merged prep: a0cast + 3x wcast in one launch -------------
__device__ __forceinline__ void wcast_tile(const float* __restrict__ W,
                                           short* __restrict__ Wt, int K, int N,
                                           int n0, int k0, int t) {
    __shared__ float tile[64][65];
    int r = t >> 2, c4 = (t & 3) * 16;
    const float* src = W + (size_t)(k0 + r) * N + n0 + c4;
    float4 f0 = *(const float4*)(src);
    float4 f1 = *(const float4*)(src + 4);
    float4 f2 = *(const float4*)(src + 8);
    float4 f3 = *(const float4*)(src + 12);
    tile[r][c4 + 0] = f0.x;  tile[r][c4 + 1] = f0.y;  tile[r][c4 + 2] = f0.z;  tile[r][c4 + 3] = f0.w;
    tile[r][c4 + 4] = f1.x;  tile[r][c4 + 5] = f1.y;  tile[r][c4 + 6] = f1.z;  tile[r][c4 + 7] = f1.w;
    tile[r][c4 + 8] = f2.x;  tile[r][c4 + 9] = f2.y;  tile[r][c4 + 10] = f2.z; tile[r][c4 + 11] = f2.w;
    tile[r][c4 + 12] = f3.x; tile[r][c4 + 13] = f3.y; tile[r][c4 + 14] = f3.z; tile[r][c4 + 15] = f3.w;
    __syncthreads();
    short* dst = Wt + (size_t)(n0 + r) * K + k0 + c4;
    short8 o1, o2;
#pragma unroll
    for (int q = 0; q < 8; ++q) o1[q] = f2bf(tile[c4 + q][r]);
#pragma unroll
    for (int q = 0; q < 8; ++q) o2[q] = f2bf(tile[c4 + 8 + q][r]);
    *(short8*)(dst) = o1;
    *(short8*)(dst + 8) = o2;
}

__global__ __launch_bounds__(256) void prep(const float* __restrict__ we,
                                            const float* __restrict__ emb_w,
                                            const float* __restrict__ qkv_w0,
                                            const float* __restrict__ qkv_w1,
                                            short* __restrict__ A0,
                                            short* __restrict__ WtE,
                                            short* __restrict__ Wt0,
                                            short* __restrict__ Wt1) {
    int bid = blockIdx.x, t = threadIdx.x;
    if (bid < 1536) {                       // a0cast
        int e = bid * 256 + t;
        int m = e / 96, dc = (e % 96) * 8;
        int b = m & 3, s = m >> 2;
        const float* src = we + (size_t)(b * 1024 + s) * 768 + dc;
        float4 f0 = *(const float4*)(src);
        float4 f1 = *(const float4*)(src + 4);
        short8 o;
        o[0] = f2bf(f0.x); o[1] = f2bf(f0.y); o[2] = f2bf(f0.z); o[3] = f2bf(f0.w);
        o[4] = f2bf(f1.x); o[5] = f2bf(f1.y); o[6] = f2bf(f1.z); o[7] = f2bf(f1.w);
        *(short8*)(A0 + (size_t)m * 768 + dc) = o;
    } else if (bid < 1728) {                // emb_w -> WtE  (K=768, N=1024)
        int tt = bid - 1536;
        wcast_tile(emb_w, WtE, 768, 1024, (tt & 15) * 64, (tt >> 4) * 64, t);
    } else if (bid < 2496) {                // qkv_w0 -> Wt0 (K=1024, N=3072)
        int tt = bid - 1728;
        wcast_tile(qkv_w0, Wt0, 1024, 3072, (tt % 48) * 64, (tt / 48) * 64, t);
    } else {                                // qkv_w1 -> Wt1
        int tt = bid - 2496;
        wcast_tile(qkv_w1, Wt1, 1024, 3072, (tt % 48) * 64, (tt / 48) * 64, t);
    }
}

// ---------------- GEMM: C[M][N] = A[M][K] @ Wt[N][K]^T (+bias), bf16 MFMA ---
// 128x128 tile, BK=64, XOR-swizzled LDS (conflict-free b128 frag reads),
// global_load_lds(16B) staging, swapped-operand MFMA -> short4 vector stores.
// PACK=1: epilogue scatters straight into Qp/Kp/Vp [bn][t][d] (Q scaled 1/8),
// eliminating the heads buffer + pack round-trip.
template <int PACK>
__global__ __launch_bounds__(256) void gemm_bt(const short* __restrict__ A,
                                               const short* __restrict__ Bt,
                                               short* __restrict__ C,
                                               const float* __restrict__ bias,
                                               int K, int N,
                                               short* __restrict__ Qp,
                                               short* __restrict__ Kp,
                                               short* __restrict__ Vp) {
    __shared__ __align__(16) short sA[128 * 64];
    __shared__ __align__(16) short sB[128 * 64];
    int n0 = blockIdx.x * 128, m0 = blockIdx.y * 128;
    int tid = threadIdx.x;
    int lane = tid & 63, w = tid >> 6;
    int wm = (w >> 1) * 64, wn = (w & 1) * 64;
    int l15 = lane & 15, quad = lane >> 4;
    int lrow = lane >> 3, lchunk = (lane & 7) ^ lrow;  // staging swizzle

    floatx4 zero = {0.f, 0.f, 0.f, 0.f};
    floatx4 acc[4][4];
#pragma unroll
    for (int i = 0; i < 4; ++i)
#pragma unroll
        for (int j = 0; j < 4; ++j) acc[i][j] = zero;

    for (int k0 = 0; k0 < K; k0 += 64) {
#pragma unroll
        for (int c = 0; c < 4; ++c) {
            int r0 = w * 32 + c * 8;
            int row = r0 + lrow;
            gl_lds16(A + (size_t)(m0 + row) * K + k0 + lchunk * 8, sA + r0 * 64);
            gl_lds16(Bt + (size_t)(n0 + row) * K + k0 + lchunk * 8, sB + r0 * 64);
        }
        __syncthreads();
#pragma unroll
        for (int h = 0; h < 2; ++h) {
            int sw = ((h * 4 + quad) ^ (l15 & 7)) * 8;   // swizzled chunk offset
            short8 af[4], bfr[4];
#pragma unroll
            for (int i = 0; i < 4; ++i) {
                af[i]  = *(const short8*)(sA + (wm + i * 16 + l15) * 64 + sw);
                bfr[i] = *(const short8*)(sB + (wn + i * 16 + l15) * 64 + sw);
            }
#pragma unroll
            for (int i = 0; i < 4; ++i)
#pragma unroll
                for (int j = 0; j < 4; ++j)
                    acc[i][j] = __builtin_amdgcn_mfma_f32_16x16x32_bf16(bfr[j], af[i], acc[i][j], 0, 0, 0);
        }
        __syncthreads();
    }
    // acc[i][j][r] = C[m0+wm+i*16+l15][n0+wn+j*16+quad*4+r]
#pragma unroll
    for (int i = 0; i < 4; ++i) {
        int row = m0 + wm + i * 16 + l15;
#pragma unroll
        for (int j = 0; j < 4; ++j) {
            int colb = n0 + wn + j * 16 + quad * 4;
            if (PACK == 0) {
                float4 bv = bias ? *(const float4*)(bias + colb) : float4{0.f, 0.f, 0.f, 0.f};
                short4v st;
                st[0] = f2bf(acc[i][j][0] + bv.x);
                st[1] = f2bf(acc[i][j][1] + bv.y);
                st[2] = f2bf(acc[i][j][2] + bv.z);
                st[3] = f2bf(acc[i][j][3] + bv.w);
                *(short4v*)(C + (size_t)row * N + colb) = st;
            } else {
                // colb in [0,3072): sel {q,k,v}, head, d; row -> (s,b)
                int sel = colb >> 10, nn = colb & 1023;
                int bn = ((row & 3) << 4) + (nn >> 6);
                size_t idx = (size_t)bn * 65536 + (size_t)(row >> 2) * 64 + (nn & 63);
                float sc = (sel == 0) ? 0.125f : 1.0f;
                short4v st;
#pragma unroll
                for (int r = 0; r < 4; ++r) st[r] = f2bf(acc[i][j][r] * sc);
                short* dst = (sel == 0) ? Qp : (sel == 1 ? Kp : Vp);
                *(short4v*)(dst + idx) = st;
            }
        }
    }
}

// ---------------- pack_v: Vp [bn][t][d] -> Vtp [bn][d][t] (transpose only) --
__global__ __launch_bounds__(256) void pack_v(const short* __restrict__ Vp,
                                              short* __restrict__ Vtp) {
    __shared__ short vt[64][72];
    int bn = blockIdx.y;
    int t0 = blockIdx.x * 64;
    int t = threadIdx.x;
#pragma unroll
    for (int h = 0; h < 2; ++h) {
        int c = t + h * 256;
        int tt = c >> 3, off = (c & 7) * 8;
        short8 v = *(const short8*)(Vp + (size_t)bn * 65536 + (size_t)(t0 + tt) * 64 + off);
#pragma unroll
        for (int e = 0; e < 8; ++e) vt[tt][off + e] = v[e];
    }
    __syncthreads();
#pragma unroll
    for (int h = 0; h < 2; ++h) {
        int c = t + h * 256;
        int d = c >> 3, joff = (c & 7) * 8;
        short8 o;
#pragma unroll
        for (int e = 0; e < 8; ++e) o[e] = vt[joff + e][d];
        *(short8*)(Vtp + (size_t)bn * 65536 + (size_t)d * 1024 + t0 + joff) = o;
    }
}

// ---------------- flash attention, 16 i-rows per wave (IBLK=16) ------------
// Occupancy probe: 4096 single-wave blocks = 4 waves/SIMD (was 2). Per-wave
// serial chain halves; resident-wave overlap doubles. Swapped-operand MFMA
// as before; no __syncthreads (single wave); K/V register-pipelined 2-deep.
// XCD-aware bid mapping: xcd = bid&7 owns 8 bn -> per-XCD K/V set = 2 MB < L2.
// L2 (layer-2) additionally spills unnormalized exp(S) tiles to Pp[bn][i][j] bf16.
template <bool L2>
__global__ __launch_bounds__(64) void fattn(const short* __restrict__ Qp,
                                            const short* __restrict__ Kp,
                                            const short* __restrict__ Vtp,
                                            void* __restrict__ Optr,
                                            float* __restrict__ linv,
                                            short* __restrict__ Pp) {
    __shared__ __align__(16) short plds[2][16 * 32];
    int bid = blockIdx.x;                 // 0..4095
    int xcd = bid & 7, wid = bid >> 3;    // wid 0..511
    int bn = xcd * 8 + (wid >> 6);        // 8 bn per XCD -> K/V L2-resident
    int i0 = (wid & 63) * 16;
    int b = bn >> 4, n = bn & 15;
    int lane = threadIdx.x, l15 = lane & 15, quad = lane >> 4;
    const short* Qb = Qp + (size_t)bn * 65536;
    const short* Kb = Kp + (size_t)bn * 65536;
    const short* Vb = Vtp + (size_t)bn * 65536;

    short8 qf0 = *(const short8*)(Qb + (i0 + l15) * 64 + quad * 8);
    short8 qf1 = *(const short8*)(Qb + (i0 + l15) * 64 + 32 + quad * 8);
    floatx4 zero = {0.f, 0.f, 0.f, 0.f};
    floatx4 o[4];
#pragma unroll
    for (int tt = 0; tt < 4; ++tt) o[tt] = zero;
    float lsum = 0.f;   // per-lane partial; quad-reduce deferred to end

    // 2-deep pipeline registers: current (kc/vc) and next (kn/vn)
    short8 kc[2][2], vc[4], kn[2][2], vn[4];
#pragma unroll
    for (int jb = 0; jb < 2; ++jb) {
        const short* kr = Kb + (jb * 16 + l15) * 64 + quad * 8;
        kc[jb][0] = *(const short8*)(kr);
        kc[jb][1] = *(const short8*)(kr + 32);
    }
#pragma unroll
    for (int tt = 0; tt < 4; ++tt)
        vc[tt] = *(const short8*)(Vb + (tt * 16 + l15) * 1024 + quad * 8);

    int buf = 0;
#pragma unroll 2
    for (int j0 = 0; j0 < 1024; j0 += 32) {
        if (j0 + 32 < 1024) {   // prefetch next K/V tile (uniform branch)
#pragma unroll
            for (int jb = 0; jb < 2; ++jb) {
                const short* kr = Kb + (j0 + 32 + jb * 16 + l15) * 64 + quad * 8;
                kn[jb][0] = *(const short8*)(kr);
                kn[jb][1] = *(const short8*)(kr + 32);
            }
#pragma unroll
            for (int tt = 0; tt < 4; ++tt)
                vn[tt] = *(const short8*)(Vb + (tt * 16 + l15) * 1024 + j0 + 32 + quad * 8);
        }
#pragma unroll
        for (int jb = 0; jb < 2; ++jb) {
            floatx4 s = zero;
            s = __builtin_amdgcn_mfma_f32_16x16x32_bf16(kc[jb][0], qf0, s, 0, 0, 0);
            s = __builtin_amdgcn_mfma_f32_16x16x32_bf16(kc[jb][1], qf1, s, 0, 0, 0);
            short4v pk;
            float ls = 0.f;
#pragma unroll
            for (int r = 0; r < 4; ++r) {
                float p = __builtin_amdgcn_exp2f(s[r] * LOG2E);
                ls += p;
                pk[r] = f2bf(p);
            }
            lsum += ls;
            *(short4v*)(plds[buf] + l15 * 32 + jb * 16 + quad * 4) = pk;
            if (L2) {
                // unnormalized P tile -> Pp[bn][i][j], 8B per lane, 32B/row segment
                *(short4v*)(Pp + (size_t)bn * 1048576 +
                            (size_t)(i0 + l15) * 1024 + j0 + jb * 16 + quad * 4) = pk;
            }
        }
        short8 pa = *(const short8*)(plds[buf] + l15 * 32 + quad * 8);
#pragma unroll
        for (int tt = 0; tt < 4; ++tt)
            o[tt] = __builtin_amdgcn_mfma_f32_16x16x32_bf16(vc[tt], pa, o[tt], 0, 0, 0);
        // rotate pipeline regs (copy-propagated by the 2x unroll)
#pragma unroll
        for (int jb = 0; jb < 2; ++jb) { kc[jb][0] = kn[jb][0]; kc[jb][1] = kn[jb][1]; }
#pragma unroll
        for (int tt = 0; tt < 4; ++tt) vc[tt] = vn[tt];
        buf ^= 1;
    }
    float t = lsum;
    t += __shfl_xor(t, 16);
    t += __shfl_xor(t, 32);
    float rinv = 1.f / t;                 // row i = i0 + l15
    if (L2 && quad == 0) {
        linv[bn * 1024 + i0 + l15] = rinv;
    }
    // o[tt][r] = out[i = i0+l15][d = tt*16+quad*4+r]
#pragma unroll
    for (int tt = 0; tt < 4; ++tt) {
        int row = i0 + l15;
        int colb = n * 64 + tt * 16 + quad * 4;
        size_t idx = (size_t)(row * 4 + b) * 1024 + colb;
        if (L2) {
            float4 v;
            v.x = o[tt][0] * rinv;
            v.y = o[tt][1] * rinv;
            v.z = o[tt][2] * rinv;
            v.w = o[tt][3] * rinv;
            *(float4*)((float*)Optr + idx) = v;
        } else {
            short4v st;
#pragma unroll
            for (int r = 0; r < 4; ++r) st[r] = f2bf(o[tt][r] * rinv);
            *(short4v*)((short*)Optr + idx) = st;
        }
    }
}

// ---------------- P finalize: stream Pp bf16, scale by linv, transpose to
// attn_maps [i][j][b*16+n] fp32 with coalesced float4 writes. No recompute.
__global__ __launch_bounds__(256) void pfin(const short* __restrict__ Pp,
                                            const float* __restrict__ linv,
                                            float* __restrict__ Pout) {
    __shared__ short sP[64 * 512];  // [bn][16 i][32 j] bf16 = 64 KB
    int j0 = blockIdx.x * 32, i0 = blockIdx.y * 16;
    int t = threadIdx.x;
    // fill: 4096 x 16B chunks; chunk c -> bn = c>>6, ii = (c&63)>>2, part = c&3
#pragma unroll
    for (int h = 0; h < 16; ++h) {
        int c = t + h * 256;
        int bn = c >> 6, rem = c & 63, ii = rem >> 2, part = rem & 3;
        short8 v = *(const short8*)(Pp + (size_t)bn * 1048576 +
                                    (size_t)(i0 + ii) * 1024 + j0 + part * 8);
        float li = linv[bn * 1024 + i0 + ii];
        short8 sv;
#pragma unroll
        for (int e = 0; e < 8; ++e) sv[e] = f2bf(bf2f(v[e]) * li);
        *(short8*)(sP + bn * 512 + ii * 32 + part * 8) = sv;  // addr = c*16B, conflict-free
    }
    __syncthreads();
    int ii = t >> 4, q = t & 15;
    float* dst = Pout + (size_t)(i0 + ii) * 65536 + j0 * 64 + q * 128;
#pragma unroll
    for (int e4 = 0; e4 < 32; ++e4) {
        int pos = q * 128 + e4 * 4;
        int jj = pos >> 6, bnb = pos & 63;
        float4 v;
        v.x = bf2f(sP[(bnb + 0) * 512 + ii * 32 + jj]);
        v.y = bf2f(sP[(bnb + 1) * 512 + ii * 32 + jj]);
        v.z = bf2f(sP[(bnb + 2) * 512 + ii * 32 + jj]);
        v.w = bf2f(sP[(bnb + 3) * 512 + ii * 32 + jj]);
        *(float4*)(dst + e4 * 4) = v;
    }
}

extern "C" void kernel_launch(void* const* d_in, const int* in_sizes, int n_in,
                              void* d_out, int out_size, void* d_ws, size_t ws_size,
                              hipStream_t stream) {
    const float* word_emb = (const float*)d_in[0];
    const float* emb_w    = (const float*)d_in[1];
    const float* emb_b    = (const float*)d_in[2];
    const float* qkv_w0   = (const float*)d_in[3];
    const float* qkv_w1   = (const float*)d_in[4];
    float* out0 = (float*)d_out;                 // core_out [1024,4,1024] fp32
    float* out1 = out0 + 4194304;                // attn_maps [1024,1024,4,16] fp32

    char* ws = (char*)d_ws;
    short* A0    = (short*)(ws);                 // 4096x768  bf16 (6 MB)
    short* WtE   = (short*)(ws + 6291456);       // 1024x768  (1.5 MB)
    short* Wt0   = (short*)(ws + 7864320);       // 3072x1024 (6 MB)
    short* Wt1   = (short*)(ws + 14155776);      // 3072x1024 (6 MB)
    short* hbuf  = (short*)(ws + 20447232);      // 4096x1024 (8 MB)
    short* h2    = (short*)(ws + 28835840);      // 4096x1024 (8 MB)
    short* Qp    = (short*)(ws + 37224448);      // 64x1024x64 (8 MB)
    short* Kp    = (short*)(ws + 45613056);      // 8 MB
    short* Vp    = (short*)(ws + 54001664);      // 8 MB  [bn][t][d]
    short* Vtp   = (short*)(ws + 62390272);      // 8 MB  [bn][d][t]
    float* linv  = (float*)(ws + 70778880);      // 64x1024 fp32 (256 KB)
    short* Pp    = (short*)(ws + 71041024);      // 64x1024x1024 bf16 (134 MB)

    prep<<<3264, 256, 0, stream>>>(word_emb, emb_w, qkv_w0, qkv_w1, A0, WtE, Wt0, Wt1);

    gemm_bt<0><<<dim3(8, 32), 256, 0, stream>>>(A0, WtE, hbuf, emb_b, 768, 1024,
                                                nullptr, nullptr, nullptr);
    // layer 1
    gemm_bt<1><<<dim3(24, 32), 256, 0, stream>>>(hbuf, Wt0, nullptr, nullptr, 1024, 3072,
                                                 Qp, Kp, Vp);
    pack_v<<<dim3(16, 64), 256, 0, stream>>>(Vp, Vtp);
    fattn<false><<<4096, 64, 0, stream>>>(Qp, Kp, Vtp, (void*)h2, nullptr, nullptr);
    // layer 2
    gemm_bt<1><<<dim3(24, 32), 256, 0, stream>>>(h2, Wt1, nullptr, nullptr, 1024, 3072,
                                                 Qp, Kp, Vp);
    pack_v<<<dim3(16, 64), 256, 0, stream>>>(Vp, Vtp);
    fattn<true><<<4096, 64, 0, stream>>>(Qp, Kp, Vtp, (void*)out0, linv, Pp);
    pfin<<<dim3(32, 64), 256, 0, stream>>>(Pp, linv, out1);
}

// Round 4
// 628.027 us; speedup vs baseline: 1.2345x; 1.2345x over previous
//
#include <hip/hip_runtime.h>

// Shapes: S=1024 qlen, B=4 bsz, E=768 d_embed, D=1024 d_model, H=16 heads, Dh=64.
// M = S*B = 4096 rows everywhere (row m = i*4 + b).
#define LOG2E 1.44269504088896340736f

typedef __attribute__((ext_vector_type(8))) short short8;   // 8 x bf16 fragment
typedef __attribute__((ext_vector_type(4))) short short4v;  // 4 x bf16 (8B)
typedef __attribute__((ext_vector_type(4))) float floatx4;  // MFMA C/D fragment

__device__ __forceinline__ float bf2f(short s) {
    union { float f; unsigned u; } v; v.u = ((unsigned)(unsigned short)s) << 16; return v.f;
}
__device__ __forceinline__ short f2bf(float f) {
    union { float f; unsigned u; } v; v.f = f;
    unsigned u = v.u;
    u += 0x7FFFu + ((u >> 16) & 1u);   // RNE
    return (short)(u >> 16);
}

// async global->LDS, 16B per lane; LDS dest = wave-uniform base + lane*16
__device__ __forceinline__ void gl_lds16(const void* g, void* l) {
    __builtin_amdgcn_global_load_lds((const __attribute__((address_space(1))) void*)g,
                                     (__attribute__((address_space(3))) void*)l, 16, 0, 0);
}

// ---------------- merged prep: a0cast + 3x wcast in one launch -------------
__device__ __forceinline__ void wcast_tile(const float* __restrict__ W,
                                           short* __restrict__ Wt, int K, int N,
                                           int n0, int k0, int t) {
    __shared__ float tile[64][65];
    int r = t >> 2, c4 = (t & 3) * 16;
    const float* src = W + (size_t)(k0 + r) * N + n0 + c4;
    float4 f0 = *(const float4*)(src);
    float4 f1 = *(const float4*)(src + 4);
    float4 f2 = *(const float4*)(src + 8);
    float4 f3 = *(const float4*)(src + 12);
    tile[r][c4 + 0] = f0.x;  tile[r][c4 + 1] = f0.y;  tile[r][c4 + 2] = f0.z;  tile[r][c4 + 3] = f0.w;
    tile[r][c4 + 4] = f1.x;  tile[r][c4 + 5] = f1.y;  tile[r][c4 + 6] = f1.z;  tile[r][c4 + 7] = f1.w;
    tile[r][c4 + 8] = f2.x;  tile[r][c4 + 9] = f2.y;  tile[r][c4 + 10] = f2.z; tile[r][c4 + 11] = f2.w;
    tile[r][c4 + 12] = f3.x; tile[r][c4 + 13] = f3.y; tile[r][c4 + 14] = f3.z; tile[r][c4 + 15] = f3.w;
    __syncthreads();
    short* dst = Wt + (size_t)(n0 + r) * K + k0 + c4;
    short8 o1, o2;
#pragma unroll
    for (int q = 0; q < 8; ++q) o1[q] = f2bf(tile[c4 + q][r]);
#pragma unroll
    for (int q = 0; q < 8; ++q) o2[q] = f2bf(tile[c4 + 8 + q][r]);
    *(short8*)(dst) = o1;
    *(short8*)(dst + 8) = o2;
}

__global__ __launch_bounds__(256) void prep(const float* __restrict__ we,
                                            const float* __restrict__ emb_w,
                                            const float* __restrict__ qkv_w0,
                                            const float* __restrict__ qkv_w1,
                                            short* __restrict__ A0,
                                            short* __restrict__ WtE,
                                            short* __restrict__ Wt0,
                                            short* __restrict__ Wt1) {
    int bid = blockIdx.x, t = threadIdx.x;
    if (bid < 1536) {                       // a0cast
        int e = bid * 256 + t;
        int m = e / 96, dc = (e % 96) * 8;
        int b = m & 3, s = m >> 2;
        const float* src = we + (size_t)(b * 1024 + s) * 768 + dc;
        float4 f0 = *(const float4*)(src);
        float4 f1 = *(const float4*)(src + 4);
        short8 o;
        o[0] = f2bf(f0.x); o[1] = f2bf(f0.y); o[2] = f2bf(f0.z); o[3] = f2bf(f0.w);
        o[4] = f2bf(f1.x); o[5] = f2bf(f1.y); o[6] = f2bf(f1.z); o[7] = f2bf(f1.w);
        *(short8*)(A0 + (size_t)m * 768 + dc) = o;
    } else if (bid < 1728) {                // emb_w -> WtE  (K=768, N=1024)
        int tt = bid - 1536;
        wcast_tile(emb_w, WtE, 768, 1024, (tt & 15) * 64, (tt >> 4) * 64, t);
    } else if (bid < 2496) {                // qkv_w0 -> Wt0 (K=1024, N=3072)
        int tt = bid - 1728;
        wcast_tile(qkv_w0, Wt0, 1024, 3072, (tt % 48) * 64, (tt / 48) * 64, t);
    } else {                                // qkv_w1 -> Wt1
        int tt = bid - 2496;
        wcast_tile(qkv_w1, Wt1, 1024, 3072, (tt % 48) * 64, (tt / 48) * 64, t);
    }
}

// ---------------- GEMM: C[M][N] = A[M][K] @ Wt[N][K]^T (+bias), bf16 MFMA ---
// 128x128 tile, BK=64, XOR-swizzled LDS (conflict-free b128 frag reads),
// global_load_lds(16B) staging, swapped-operand MFMA -> short4 vector stores.
// PACK=1: epilogue scatters straight into Qp/Kp/Vp [bn][t][d] (Q scaled 1/8),
// eliminating the heads buffer + pack round-trip.
template <int PACK>
__global__ __launch_bounds__(256) void gemm_bt(const short* __restrict__ A,
                                               const short* __restrict__ Bt,
                                               short* __restrict__ C,
                                               const float* __restrict__ bias,
                                               int K, int N,
                                               short* __restrict__ Qp,
                                               short* __restrict__ Kp,
                                               short* __restrict__ Vp) {
    __shared__ __align__(16) short sA[128 * 64];
    __shared__ __align__(16) short sB[128 * 64];
    int n0 = blockIdx.x * 128, m0 = blockIdx.y * 128;
    int tid = threadIdx.x;
    int lane = tid & 63, w = tid >> 6;
    int wm = (w >> 1) * 64, wn = (w & 1) * 64;
    int l15 = lane & 15, quad = lane >> 4;
    int lrow = lane >> 3, lchunk = (lane & 7) ^ lrow;  // staging swizzle

    floatx4 zero = {0.f, 0.f, 0.f, 0.f};
    floatx4 acc[4][4];
#pragma unroll
    for (int i = 0; i < 4; ++i)
#pragma unroll
        for (int j = 0; j < 4; ++j) acc[i][j] = zero;

    for (int k0 = 0; k0 < K; k0 += 64) {
#pragma unroll
        for (int c = 0; c < 4; ++c) {
            int r0 = w * 32 + c * 8;
            int row = r0 + lrow;
            gl_lds16(A + (size_t)(m0 + row) * K + k0 + lchunk * 8, sA + r0 * 64);
            gl_lds16(Bt + (size_t)(n0 + row) * K + k0 + lchunk * 8, sB + r0 * 64);
        }
        __syncthreads();
#pragma unroll
        for (int h = 0; h < 2; ++h) {
            int sw = ((h * 4 + quad) ^ (l15 & 7)) * 8;   // swizzled chunk offset
            short8 af[4], bfr[4];
#pragma unroll
            for (int i = 0; i < 4; ++i) {
                af[i]  = *(const short8*)(sA + (wm + i * 16 + l15) * 64 + sw);
                bfr[i] = *(const short8*)(sB + (wn + i * 16 + l15) * 64 + sw);
            }
#pragma unroll
            for (int i = 0; i < 4; ++i)
#pragma unroll
                for (int j = 0; j < 4; ++j)
                    acc[i][j] = __builtin_amdgcn_mfma_f32_16x16x32_bf16(bfr[j], af[i], acc[i][j], 0, 0, 0);
        }
        __syncthreads();
    }
    // acc[i][j][r] = C[m0+wm+i*16+l15][n0+wn+j*16+quad*4+r]
#pragma unroll
    for (int i = 0; i < 4; ++i) {
        int row = m0 + wm + i * 16 + l15;
#pragma unroll
        for (int j = 0; j < 4; ++j) {
            int colb = n0 + wn + j * 16 + quad * 4;
            if (PACK == 0) {
                float4 bv = bias ? *(const float4*)(bias + colb) : float4{0.f, 0.f, 0.f, 0.f};
                short4v st;
                st[0] = f2bf(acc[i][j][0] + bv.x);
                st[1] = f2bf(acc[i][j][1] + bv.y);
                st[2] = f2bf(acc[i][j][2] + bv.z);
                st[3] = f2bf(acc[i][j][3] + bv.w);
                *(short4v*)(C + (size_t)row * N + colb) = st;
            } else {
                // colb in [0,3072): sel {q,k,v}, head, d; row -> (s,b)
                int sel = colb >> 10, nn = colb & 1023;
                int bn = ((row & 3) << 4) + (nn >> 6);
                size_t idx = (size_t)bn * 65536 + (size_t)(row >> 2) * 64 + (nn & 63);
                float sc = (sel == 0) ? 0.125f : 1.0f;
                short4v st;
#pragma unroll
                for (int r = 0; r < 4; ++r) st[r] = f2bf(acc[i][j][r] * sc);
                short* dst = (sel == 0) ? Qp : (sel == 1 ? Kp : Vp);
                *(short4v*)(dst + idx) = st;
            }
        }
    }
}

// ---------------- pack_v: Vp [bn][t][d] -> Vtp [bn][d][t] (transpose only) --
__global__ __launch_bounds__(256) void pack_v(const short* __restrict__ Vp,
                                              short* __restrict__ Vtp) {
    __shared__ short vt[64][72];
    int bn = blockIdx.y;
    int t0 = blockIdx.x * 64;
    int t = threadIdx.x;
#pragma unroll
    for (int h = 0; h < 2; ++h) {
        int c = t + h * 256;
        int tt = c >> 3, off = (c & 7) * 8;
        short8 v = *(const short8*)(Vp + (size_t)bn * 65536 + (size_t)(t0 + tt) * 64 + off);
#pragma unroll
        for (int e = 0; e < 8; ++e) vt[tt][off + e] = v[e];
    }
    __syncthreads();
#pragma unroll
    for (int h = 0; h < 2; ++h) {
        int c = t + h * 256;
        int d = c >> 3, joff = (c & 7) * 8;
        short8 o;
#pragma unroll
        for (int e = 0; e < 8; ++e) o[e] = vt[joff + e][d];
        *(short8*)(Vtp + (size_t)bn * 65536 + (size_t)d * 1024 + t0 + joff) = o;
    }
}

// ---------------- flash attention, 4 waves/block sharing K/V tiles via LDS --
// Block covers 128 i-rows (wave w: i0 = iblk*128 + w*32; per-wave internals =
// round-2 IBLK=32 swapped-operand structure). Per j-tile (32 j), the block
// stages ONE K tile (32x64 bf16, XOR-swizzled via pre-swizzled global source)
// and ONE V^T tile (64 rows x 80B padded -> conflict-free b128 reads) with
// global_load_lds, double-buffered: STAGE(next) -> compute(cur) -> barrier.
// K/V global traffic drops 4x vs 1-wave blocks (round-3 showed traffic-bound).
// XCD map: xcd = bid&7 owns 8 bn -> per-XCD K/V set ~2 MB, L2-resident.
// L2 (layer-2) additionally spills unnormalized exp(S) tiles to Pp[bn][i][j].
template <bool L2>
__global__ __launch_bounds__(256) void fattn(const short* __restrict__ Qp,
                                             const short* __restrict__ Kp,
                                             const short* __restrict__ Vtp,
                                             void* __restrict__ Optr,
                                             float* __restrict__ linv,
                                             short* __restrict__ Pp) {
    __shared__ __align__(16) short sK[2][32 * 64];   // [j][k], rows 128B, swizzled
    __shared__ __align__(16) short sV[2][64 * 40];   // [d][j+pad], rows 80B, linear
    __shared__ __align__(16) short plds[4][2][32 * 32];
    int bid = blockIdx.x;                 // 0..511
    int xcd = bid & 7, rr = bid >> 3;     // rr 0..63
    int bn = xcd * 8 + (rr & 7);          // 8 bn per XCD
    int iblk = rr >> 3;                   // 0..7
    int tid = threadIdx.x, w = tid >> 6, lane = tid & 63;
    int i0 = iblk * 128 + w * 32;
    int b = bn >> 4, n = bn & 15;
    int l15 = lane & 15, quad = lane >> 4;
    const short* Qb = Qp + (size_t)bn * 65536;
    const char* Kb = (const char*)(Kp + (size_t)bn * 65536);
    const char* Vb = (const char*)(Vtp + (size_t)bn * 65536);

    // staging lane constants
    int kr_ = lane >> 3, ko_ = lane & 7;            // K: row-in-8, chunk
    size_t koff = (size_t)kr_ * 128 + ((ko_ ^ kr_) * 16);  // pre-swizzled source
    // V: per-call row/col from LDS byte beta = c*1024 + lane*16 (rows 80B)
    int vr_[5], vc_[5];
#pragma unroll
    for (int c = 0; c < 5; ++c) {
        int beta = c * 1024 + lane * 16;
        vr_[c] = beta / 80;
        vc_[c] = (beta % 80) & 63;        // pad chunk -> dup chunk 0 (unread)
    }

#define KCALL(B, J0, c) \
    gl_lds16(Kb + (size_t)((J0) + 8 * (c)) * 128 + koff, (char*)sK[B] + (c) * 1024)
#define VCALL(B, J0, c) \
    gl_lds16(Vb + (size_t)vr_[c] * 2048 + (size_t)(J0) * 2 + vc_[c], (char*)sV[B] + (c) * 1024)
#define STAGE(B, J0) do { \
        if (w == 0)      { KCALL(B, J0, 0); KCALL(B, J0, 1); } \
        else if (w == 1) { KCALL(B, J0, 2); KCALL(B, J0, 3); } \
        else if (w == 2) { VCALL(B, J0, 0); VCALL(B, J0, 1); VCALL(B, J0, 2); } \
        else             { VCALL(B, J0, 3); VCALL(B, J0, 4); } \
    } while (0)

    short8 qf[2][2];
#pragma unroll
    for (int ib = 0; ib < 2; ++ib) {
        qf[ib][0] = *(const short8*)(Qb + (i0 + ib * 16 + l15) * 64 + quad * 8);
        qf[ib][1] = *(const short8*)(Qb + (i0 + ib * 16 + l15) * 64 + 32 + quad * 8);
    }
    floatx4 zero = {0.f, 0.f, 0.f, 0.f};
    floatx4 o[2][4];
#pragma unroll
    for (int ib = 0; ib < 2; ++ib)
#pragma unroll
        for (int tt = 0; tt < 4; ++tt) o[ib][tt] = zero;
    float lsum[2] = {0.f, 0.f};   // per-lane partial; quad-reduce deferred to end

    STAGE(0, 0);
    __syncthreads();              // drains vmcnt(0): buf0 ready

    int buf = 0;
#pragma unroll 2
    for (int j0 = 0; j0 < 1024; j0 += 32) {
        if (j0 + 32 < 1024) STAGE(buf ^ 1, j0 + 32);   // async prefetch next tile
        short* pw = plds[w][buf];
        int r7 = l15 & 7;
#pragma unroll
        for (int jb = 0; jb < 2; ++jb) {
            const short* kbase = sK[buf] + (jb * 16 + l15) * 64;
            short8 kf0 = *(const short8*)(kbase + ((quad ^ r7) * 8));
            short8 kf1 = *(const short8*)(kbase + (((4 + quad) ^ r7) * 8));
#pragma unroll
            for (int ib = 0; ib < 2; ++ib) {
                floatx4 s = zero;
                s = __builtin_amdgcn_mfma_f32_16x16x32_bf16(kf0, qf[ib][0], s, 0, 0, 0);
                s = __builtin_amdgcn_mfma_f32_16x16x32_bf16(kf1, qf[ib][1], s, 0, 0, 0);
                short4v pk;
                float ls = 0.f;
#pragma unroll
                for (int r = 0; r < 4; ++r) {
                    float p = __builtin_amdgcn_exp2f(s[r] * LOG2E);
                    ls += p;
                    pk[r] = f2bf(p);
                }
                lsum[ib] += ls;
                *(short4v*)(pw + (ib * 16 + l15) * 32 + jb * 16 + quad * 4) = pk;
                if (L2) {
                    // unnormalized P tile -> Pp[bn][i][j], 8B per lane
                    *(short4v*)(Pp + (size_t)bn * 1048576 +
                                (size_t)(i0 + ib * 16 + l15) * 1024 + j0 + jb * 16 + quad * 4) = pk;
                }
            }
        }
        short8 pa[2];
        pa[0] = *(const short8*)(pw + l15 * 32 + quad * 8);
        pa[1] = *(const short8*)(pw + (16 + l15) * 32 + quad * 8);
#pragma unroll
        for (int tt = 0; tt < 4; ++tt) {
            short8 vf = *(const short8*)(sV[buf] + (tt * 16 + l15) * 40 + quad * 8);
#pragma unroll
            for (int ib = 0; ib < 2; ++ib)
                o[ib][tt] = __builtin_amdgcn_mfma_f32_16x16x32_bf16(vf, pa[ib], o[ib][tt], 0, 0, 0);
        }
        __syncthreads();          // staged loads landed; readers done with buf
        buf ^= 1;
    }
#undef STAGE
#undef KCALL
#undef VCALL

    float rinv[2];
#pragma unroll
    for (int ib = 0; ib < 2; ++ib) {
        float t = lsum[ib];
        t += __shfl_xor(t, 16);
        t += __shfl_xor(t, 32);
        rinv[ib] = 1.f / t;               // row i = i0 + ib*16 + l15
    }
    if (L2 && quad == 0) {
        linv[bn * 1024 + i0 + l15] = rinv[0];
        linv[bn * 1024 + i0 + 16 + l15] = rinv[1];
    }
    // o[ib][tt][r] = out[i = i0+ib*16+l15][d = tt*16+quad*4+r]
#pragma unroll
    for (int ib = 0; ib < 2; ++ib)
#pragma unroll
        for (int tt = 0; tt < 4; ++tt) {
            int row = i0 + ib * 16 + l15;
            int colb = n * 64 + tt * 16 + quad * 4;
            size_t idx = (size_t)(row * 4 + b) * 1024 + colb;
            if (L2) {
                float4 v;
                v.x = o[ib][tt][0] * rinv[ib];
                v.y = o[ib][tt][1] * rinv[ib];
                v.z = o[ib][tt][2] * rinv[ib];
                v.w = o[ib][tt][3] * rinv[ib];
                *(float4*)((float*)Optr + idx) = v;
            } else {
                short4v st;
#pragma unroll
                for (int r = 0; r < 4; ++r) st[r] = f2bf(o[ib][tt][r] * rinv[ib]);
                *(short4v*)((short*)Optr + idx) = st;
            }
        }
}

// ---------------- P finalize: stream Pp bf16, scale by linv, transpose to
// attn_maps [i][j][b*16+n] fp32 with coalesced float4 writes. No recompute.
__global__ __launch_bounds__(256) void pfin(const short* __restrict__ Pp,
                                            const float* __restrict__ linv,
                                            float* __restrict__ Pout) {
    __shared__ short sP[64 * 512];  // [bn][16 i][32 j] bf16 = 64 KB
    int j0 = blockIdx.x * 32, i0 = blockIdx.y * 16;
    int t = threadIdx.x;
    // fill: 4096 x 16B chunks; chunk c -> bn = c>>6, ii = (c&63)>>2, part = c&3
#pragma unroll
    for (int h = 0; h < 16; ++h) {
        int c = t + h * 256;
        int bn = c >> 6, rem = c & 63, ii = rem >> 2, part = rem & 3;
        short8 v = *(const short8*)(Pp + (size_t)bn * 1048576 +
                                    (size_t)(i0 + ii) * 1024 + j0 + part * 8);
        float li = linv[bn * 1024 + i0 + ii];
        short8 sv;
#pragma unroll
        for (int e = 0; e < 8; ++e) sv[e] = f2bf(bf2f(v[e]) * li);
        *(short8*)(sP + bn * 512 + ii * 32 + part * 8) = sv;  // addr = c*16B, conflict-free
    }
    __syncthreads();
    int ii = t >> 4, q = t & 15;
    float* dst = Pout + (size_t)(i0 + ii) * 65536 + j0 * 64 + q * 128;
#pragma unroll
    for (int e4 = 0; e4 < 32; ++e4) {
        int pos = q * 128 + e4 * 4;
        int jj = pos >> 6, bnb = pos & 63;
        float4 v;
        v.x = bf2f(sP[(bnb + 0) * 512 + ii * 32 + jj]);
        v.y = bf2f(sP[(bnb + 1) * 512 + ii * 32 + jj]);
        v.z = bf2f(sP[(bnb + 2) * 512 + ii * 32 + jj]);
        v.w = bf2f(sP[(bnb + 3) * 512 + ii * 32 + jj]);
        *(float4*)(dst + e4 * 4) = v;
    }
}

extern "C" void kernel_launch(void* const* d_in, const int* in_sizes, int n_in,
                              void* d_out, int out_size, void* d_ws, size_t ws_size,
                              hipStream_t stream) {
    const float* word_emb = (const float*)d_in[0];
    const float* emb_w    = (const float*)d_in[1];
    const float* emb_b    = (const float*)d_in[2];
    const float* qkv_w0   = (const float*)d_in[3];
    const float* qkv_w1   = (const float*)d_in[4];
    float* out0 = (float*)d_out;                 // core_out [1024,4,1024] fp32
    float* out1 = out0 + 4194304;                // attn_maps [1024,1024,4,16] fp32

    char* ws = (char*)d_ws;
    short* A0    = (short*)(ws);                 // 4096x768  bf16 (6 MB)
    short* WtE   = (short*)(ws + 6291456);       // 1024x768  (1.5 MB)
    short* Wt0   = (short*)(ws + 7864320);       // 3072x1024 (6 MB)
    short* Wt1   = (short*)(ws + 14155776);      // 3072x1024 (6 MB)
    short* hbuf  = (short*)(ws + 20447232);      // 4096x1024 (8 MB)
    short* h2    = (short*)(ws + 28835840);      // 4096x1024 (8 MB)
    short* Qp    = (short*)(ws + 37224448);      // 64x1024x64 (8 MB)
    short* Kp    = (short*)(ws + 45613056);      // 8 MB
    short* Vp    = (short*)(ws + 54001664);      // 8 MB  [bn][t][d]
    short* Vtp   = (short*)(ws + 62390272);      // 8 MB  [bn][d][t]
    float* linv  = (float*)(ws + 70778880);      // 64x1024 fp32 (256 KB)
    short* Pp    = (short*)(ws + 71041024);      // 64x1024x1024 bf16 (134 MB)

    prep<<<3264, 256, 0, stream>>>(word_emb, emb_w, qkv_w0, qkv_w1, A0, WtE, Wt0, Wt1);

    gemm_bt<0><<<dim3(8, 32), 256, 0, stream>>>(A0, WtE, hbuf, emb_b, 768, 1024,
                                                nullptr, nullptr, nullptr);
    // layer 1
    gemm_bt<1><<<dim3(24, 32), 256, 0, stream>>>(hbuf, Wt0, nullptr, nullptr, 1024, 3072,
                                                 Qp, Kp, Vp);
    pack_v<<<dim3(16, 64), 256, 0, stream>>>(Vp, Vtp);
    fattn<false><<<512, 256, 0, stream>>>(Qp, Kp, Vtp, (void*)h2, nullptr, nullptr);
    // layer 2
    gemm_bt<1><<<dim3(24, 32), 256, 0, stream>>>(h2, Wt1, nullptr, nullptr, 1024, 3072,
                                                 Qp, Kp, Vp);
    pack_v<<<dim3(16, 64), 256, 0, stream>>>(Vp, Vtp);
    fattn<true><<<512, 256, 0, stream>>>(Qp, Kp, Vtp, (void*)out0, linv, Pp);
    pfin<<<dim3(32, 64), 256, 0, stream>>>(Pp, linv, out1);
}